// Round 10
// baseline (478.914 us; speedup 1.0000x reference)
//
#include <hip/hip_runtime.h>

// ---------------------------------------------------------------------------
// TransformerEncoder: B=4, S=2048, D=1024, H=16, HD=64, FF=4096
// Round 15: attention KVBLK 64 -> 128 (halve the chained-iteration count).
// Attn is now the largest kernel (~110-120us inferred) and per-tile fixed
// costs (2 barriers, prefetch, P-roundtrip) were paid every 64 keys. New
// structure: 128-key tiles; QK^T+softmax done in two 64-k register phases
// (sf stays [2][4], no extra barriers — Ps is wave-private); PV consumes all
// 128 k in one MFMA cluster. LDS 70.7KB -> 2 blocks/CU (chain-bound loop,
// TLP loss acceptable). ALL GEMM kernels frozen from R14 (33-35% MfmaUtil,
// conflicts 0, fetch near-minimal — schedule rewrites exhausted there).
// ---------------------------------------------------------------------------

typedef short bf16x8 __attribute__((ext_vector_type(8)));
typedef float f32x4 __attribute__((ext_vector_type(4)));

__device__ __forceinline__ unsigned short f2bf(float f) {
  unsigned int u = __builtin_bit_cast(unsigned int, f);
  u += 0x7fffu + ((u >> 16) & 1u);   // round-to-nearest-even
  return (unsigned short)(u >> 16);
}

__device__ __forceinline__ void gload16(const unsigned short* g, unsigned short* l) {
  __builtin_amdgcn_global_load_lds(
      (const __attribute__((address_space(1))) unsigned int*)(g),
      (__attribute__((address_space(3))) unsigned int*)(l),
      16, 0, 0);
}

// --------------------------- cast fp32 -> bf16 -----------------------------
__global__ __launch_bounds__(256) void cast_f32_bf16(
    const float* __restrict__ src, unsigned short* __restrict__ dst, int n4) {
  int i = blockIdx.x * 256 + threadIdx.x;
  if (i < n4) {
    float4 f = ((const float4*)src)[i];
    ushort4 o;
    o.x = f2bf(f.x); o.y = f2bf(f.y); o.z = f2bf(f.z); o.w = f2bf(f.w);
    ((ushort4*)dst)[i] = o;
  }
}

// ---------------- merged weight prep: 6 transposes in one kernel -----------
__global__ __launch_bounds__(256) void prep_weights(
    const float* __restrict__ qW, const float* __restrict__ kW,
    const float* __restrict__ vW, const float* __restrict__ oW,
    const float* __restrict__ w1, const float* __restrict__ w2,
    unsigned short* __restrict__ qWt, unsigned short* __restrict__ kWt,
    unsigned short* __restrict__ vWt, unsigned short* __restrict__ oWt,
    unsigned short* __restrict__ w1t, unsigned short* __restrict__ w2t) {
  const int t = blockIdx.x;
  const float* W; unsigned short* Wt; int N, K, nt, kt;
  if (t < 2048) {
    const int w = t >> 9, r = t & 511;
    nt = r & 15; kt = r >> 4; N = 1024; K = 1024;
    W  = w == 0 ? qW : w == 1 ? kW : w == 2 ? vW : oW;
    Wt = w == 0 ? qWt : w == 1 ? kWt : w == 2 ? vWt : oWt;
  } else if (t < 4096) {
    const int r = t - 2048;
    nt = r & 63; kt = r >> 6; N = 4096; K = 1024; W = w1; Wt = w1t;
  } else {
    const int r = t - 4096;
    nt = r & 15; kt = r >> 4; N = 1024; K = 4096; W = w2; Wt = w2t;
  }
  const int wave = threadIdx.x >> 6, lane = threadIdx.x & 63;
  const int n = nt * 64 + lane;
  const int k0 = kt * 32 + wave * 8;
  union { int4 v; unsigned short u[8]; } s;
#pragma unroll
  for (int j = 0; j < 8; ++j) s.u[j] = f2bf(W[(size_t)(k0 + j) * N + n]);
  *(int4*)(Wt + (size_t)n * K + k0) = s.v;
}

// ---------------- 256x256 8-phase counted-vmcnt core (B^T) -----------------
// 8 waves 2Mx4N, wave tile 128x64 (8x4 frags), BK=64 (2 kk). R9-verified.
__device__ __forceinline__ void gemm256_8ph(
    const unsigned short* __restrict__ A, const unsigned short* __restrict__ Bt,
    unsigned short* __restrict__ As, unsigned short* __restrict__ Bs,
    const int m0, const int n0, const int K, f32x4 (&acc)[8][4]) {
  const int tid = (int)threadIdx.x;
  const int w = tid >> 6, l = tid & 63;
  const int quad = l >> 4, l16 = l & 15;
  const int wm = (w >> 2) * 128, wn = (w & 3) * 64;

  const int srow = w * 8 + (l >> 3);
  const int schunk = ((l & 7) ^ (l >> 3)) * 8;
  const unsigned short* gA = A + (size_t)(m0 + srow) * K + schunk;
  const unsigned short* gB = Bt + (size_t)(n0 + srow) * K + schunk;
  const int ldsW = w * 512;

  const int xr = l16 & 7;
  const int c0 = ((0 + quad) ^ xr) * 8;
  const int c1 = ((4 + quad) ^ xr) * 8;

  bf16x8 af[4][2], bf0[2][2], bf1[2][2];

  auto STA = [&](int buf, int a, int t) {
    gload16(gA + (size_t)(a * 64) * K + t * 64,
            As + buf * 16384 + a * 4096 + ldsW);
  };
  auto STB = [&](int buf, int a, int t) {
    gload16(gB + (size_t)(a * 64) * K + t * 64,
            Bs + buf * 16384 + a * 4096 + ldsW);
  };
  auto LDA = [&](int buf, int mh) {
    const unsigned short* p = As + buf * 16384 + (wm + mh * 64 + l16) * 64;
#pragma unroll
    for (int mi = 0; mi < 4; ++mi) {
      af[mi][0] = *(const bf16x8*)(p + mi * 16 * 64 + c0);
      af[mi][1] = *(const bf16x8*)(p + mi * 16 * 64 + c1);
    }
  };
  auto LDB = [&](int buf, int nh, bf16x8 (&bf)[2][2]) {
    const unsigned short* p = Bs + buf * 16384 + (wn + nh * 32 + l16) * 64;
#pragma unroll
    for (int ni = 0; ni < 2; ++ni) {
      bf[ni][0] = *(const bf16x8*)(p + ni * 16 * 64 + c0);
      bf[ni][1] = *(const bf16x8*)(p + ni * 16 * 64 + c1);
    }
  };
  auto MM = [&](int mh, int nh, bf16x8 (&bf)[2][2]) {
    __builtin_amdgcn_s_setprio(1);
#pragma unroll
    for (int mi = 0; mi < 4; ++mi)
#pragma unroll
      for (int ni = 0; ni < 2; ++ni) {
        f32x4& a = acc[mh * 4 + mi][nh * 2 + ni];
        a = __builtin_amdgcn_mfma_f32_16x16x32_bf16(af[mi][0], bf[ni][0], a, 0, 0, 0);
        a = __builtin_amdgcn_mfma_f32_16x16x32_bf16(af[mi][1], bf[ni][1], a, 0, 0, 0);
      }
    __builtin_amdgcn_s_setprio(0);
  };

  const int NK = K >> 6;   // >= 2
  STB(0, 0, 0); STB(0, 1, 0); STB(0, 2, 0); STB(0, 3, 0);
  STA(0, 0, 0); STA(0, 2, 0); STA(0, 1, 0); STA(0, 3, 0);
  asm volatile("s_waitcnt vmcnt(2)" ::: "memory");
  __builtin_amdgcn_s_barrier();

#pragma unroll 1
  for (int t = 0; t < NK; ++t) {
    const int c = t & 1, nb = c ^ 1;
    const bool st = (t + 1 < NK);
    // ---- P1 (mh0, nh0)
    LDA(c, 0); LDB(c, 0, bf0);
    if (st) { STB(nb, 0, t + 1); STB(nb, 1, t + 1); }
    __builtin_amdgcn_s_barrier();
    asm volatile("s_waitcnt lgkmcnt(0)" ::: "memory");
    __builtin_amdgcn_sched_barrier(0);
    MM(0, 0, bf0);
    __builtin_amdgcn_s_barrier();
    // ---- P2 (mh0, nh1)
    LDB(c, 1, bf1);
    if (st) { STB(nb, 2, t + 1); STB(nb, 3, t + 1); }
    __builtin_amdgcn_s_barrier();
    asm volatile("s_waitcnt lgkmcnt(0)" ::: "memory");
    __builtin_amdgcn_sched_barrier(0);
    MM(0, 1, bf1);
    if (st) asm volatile("s_waitcnt vmcnt(4)" ::: "memory");
    else    asm volatile("s_waitcnt vmcnt(0)" ::: "memory");
    __builtin_amdgcn_s_barrier();
    // ---- P3 (mh1, nh1)
    LDA(c, 1);
    if (st) { STA(nb, 0, t + 1); STA(nb, 2, t + 1); }
    __builtin_amdgcn_s_barrier();
    asm volatile("s_waitcnt lgkmcnt(0)" ::: "memory");
    __builtin_amdgcn_sched_barrier(0);
    MM(1, 1, bf1);
    __builtin_amdgcn_s_barrier();
    // ---- P4 (mh1, nh0)
    if (st) { STA(nb, 1, t + 1); STA(nb, 3, t + 1); }
    __builtin_amdgcn_s_barrier();
    MM(1, 0, bf0);
    if (st) asm volatile("s_waitcnt vmcnt(2)" ::: "memory");
    __builtin_amdgcn_s_barrier();
  }
}

// --------------------- 256^2 GEMM (B^T) — ffn1 only ------------------------
// Grid 512 = 32mt x 16nt. Chunked XCD map (R13): 4x2 chunks of 8x8 tiles.
template <int EPI>
__global__ __launch_bounds__(512, 1) void gemm256_bt(
    const unsigned short* __restrict__ A, const unsigned short* __restrict__ Bt,
    const float* __restrict__ bias, void* __restrict__ C, int N, int K) {
  __shared__ unsigned short As[2 * 16384];
  __shared__ unsigned short Bs[2 * 16384];
  const int xcd = (int)blockIdx.x & 7, local = (int)blockIdx.x >> 3;  // 0..63
  const int mt = (xcd >> 1) * 8 + (local >> 3);
  const int nt = (xcd & 1) * 8 + (local & 7);
  const int m0 = mt * 256, n0 = nt * 256;

  f32x4 acc[8][4] = {};
  gemm256_8ph(A, Bt, As, Bs, m0, n0, K, acc);

  const int tid = (int)threadIdx.x;
  const int w = tid >> 6, l = tid & 63;
  const int quad = l >> 4, l16 = l & 15;
  const int wm = (w >> 2) * 128, wn = (w & 3) * 64;

  if (EPI == 0) {
#pragma unroll
    for (int ni = 0; ni < 4; ++ni) {
      const int col = n0 + wn + ni * 16 + l16;
      const float bv = bias[col];
#pragma unroll
      for (int mi = 0; mi < 8; ++mi) {
        const int row = m0 + wm + mi * 16 + quad * 4;
#pragma unroll
        for (int r = 0; r < 4; ++r)
          ((float*)C)[(size_t)(row + r) * N + col] = acc[mi][ni][r] + bv;
      }
    }
    return;
  }

  // coalesced bf16 path (R12-verified)
  __syncthreads();
  unsigned short* sc = (w < 4) ? (As + w * 4608) : (Bs + (w - 4) * 4608);
  const int rr8 = l >> 3, c8 = (l & 7) * 8;
#pragma unroll
  for (int half = 0; half < 2; ++half) {
#pragma unroll
    for (int ni = 0; ni < 4; ++ni) {
      const int col = n0 + wn + ni * 16 + l16;
      const float bv = bias[col];
#pragma unroll
      for (int mi2 = 0; mi2 < 4; ++mi2) {
#pragma unroll
        for (int r = 0; r < 4; ++r) {
          float v = acc[half * 4 + mi2][ni][r] + bv;
          if (EPI == 2) v = v > 0.f ? v : 0.f;
          sc[(mi2 * 16 + quad * 4 + r) * 72 + ni * 16 + l16] = f2bf(v);
        }
      }
    }
    __syncthreads();
#pragma unroll
    for (int i = 0; i < 8; ++i) {
      bf16x8 vv = *(const bf16x8*)(sc + (i * 8 + rr8) * 72 + c8);
      const int row = m0 + wm + half * 64 + i * 8 + rr8;
      *(bf16x8*)((unsigned short*)C + (size_t)row * N + n0 + wn + c8) = vv;
    }
    __syncthreads();
  }
}

// -------- 128x128 depth-3 reg-double-buffered GEMM core (R11-verified) -----
__device__ __forceinline__ void gemm128_core(
    const unsigned short* __restrict__ A, const unsigned short* __restrict__ Bt,
    unsigned short* __restrict__ As, unsigned short* __restrict__ Bs,
    const int m0, const int n0, const int K, f32x4 (&acc)[4][4]) {
  const int tid = (int)threadIdx.x;
  const int w = tid >> 6, l = tid & 63;
  const int quad = l >> 4, l16 = l & 15;
  const int wm = (w >> 1) * 64, wn = (w & 1) * 64;

  const int lr = l >> 2, lc = l & 3;
  const int swz = (lc ^ ((l >> 3) & 3)) * 8;
  const unsigned short* gA[2]; const unsigned short* gB[2];
  unsigned short* dA[2]; unsigned short* dB[2];
#pragma unroll
  for (int j = 0; j < 2; ++j) {
    const int rr = (w * 2 + j) * 16 + lr;
    gA[j] = A + (size_t)(m0 + rr) * K + swz;
    gB[j] = Bt + (size_t)(n0 + rr) * K + swz;
    dA[j] = As + (w * 2 + j) * 512;
    dB[j] = Bs + (w * 2 + j) * 512;
  }

  const int cread = (quad ^ ((l16 >> 1) & 3)) * 8;
  const int rA = (wm + l16) * 32;
  const int rB = (wn + l16) * 32;

  auto STAGE = [&](int db, int t) {
#pragma unroll
    for (int j = 0; j < 2; ++j) {
      gload16(gA[j] + t * 32, dA[j] + db * 4096);
      gload16(gB[j] + t * 32, dB[j] + db * 4096);
    }
  };
  auto DSR = [&](int db, bf16x8 (&af)[4], bf16x8 (&bf)[4]) {
    const unsigned short* pa = As + db * 4096 + rA + cread;
    const unsigned short* pb = Bs + db * 4096 + rB + cread;
#pragma unroll
    for (int ni = 0; ni < 4; ++ni) bf[ni] = *(const bf16x8*)(pb + ni * 16 * 32);
#pragma unroll
    for (int mi = 0; mi < 4; ++mi) af[mi] = *(const bf16x8*)(pa + mi * 16 * 32);
  };
  auto MM = [&](bf16x8 (&af)[4], bf16x8 (&bf)[4]) {
    __builtin_amdgcn_s_setprio(1);
#pragma unroll
    for (int mi = 0; mi < 4; ++mi)
#pragma unroll
      for (int ni = 0; ni < 4; ++ni)
        acc[mi][ni] = __builtin_amdgcn_mfma_f32_16x16x32_bf16(
            af[mi], bf[ni], acc[mi][ni], 0, 0, 0);
    __builtin_amdgcn_s_setprio(0);
  };

  bf16x8 afA[4], bfA[4], afB[4], bfB[4];

  const int NK = K >> 5;   // even, >= 4
  STAGE(0, 0); STAGE(1, 1); STAGE(2, 2);
  asm volatile("s_waitcnt vmcnt(8)" ::: "memory");
  __builtin_amdgcn_s_barrier();
  DSR(0, afA, bfA);

#define STEP128(T, afC, bfC, afN, bfN)                                \
  {                                                                   \
    const int t_ = (T);                                               \
    if (t_ + 2 < NK) asm volatile("s_waitcnt vmcnt(4)" ::: "memory"); \
    else             asm volatile("s_waitcnt vmcnt(0)" ::: "memory"); \
    __builtin_amdgcn_s_barrier();                                     \
    DSR((t_ + 1) & 3, afN, bfN);                                      \
    if (t_ + 3 < NK) STAGE((t_ + 3) & 3, t_ + 3);                     \
    MM(afC, bfC);                                                     \
  }

#pragma unroll 1
  for (int t = 0; t < NK - 2; t += 2) {
    STEP128(t, afA, bfA, afB, bfB);
    STEP128(t + 1, afB, bfB, afA, bfA);
  }
  STEP128(NK - 2, afA, bfA, afB, bfB);
  MM(afB, bfB);
#undef STEP128
}

// --------------------- 128^2 GEMM (B^T) — proj, ffn2 -----------------------
// Grid 512 = 64mt x 8nt. Chunked XCD map: 8x1 chunks of 8x8 tiles.
template <int EPI>
__global__ __launch_bounds__(256, 2) void gemm128_bt(
    const unsigned short* __restrict__ A, const unsigned short* __restrict__ Bt,
    const float* __restrict__ bias, void* __restrict__ C, int N, int K) {
  __shared__ unsigned short As[4 * 4096];
  __shared__ unsigned short Bs[4 * 4096];
  const int xcd = (int)blockIdx.x & 7, local = (int)blockIdx.x >> 3;  // 0..63
  const int mt = xcd * 8 + (local >> 3);
  const int nt = local & 7;
  const int m0 = mt * 128, n0 = nt * 128;

  f32x4 acc[4][4] = {};
  gemm128_core(A, Bt, As, Bs, m0, n0, K, acc);

  const int tid = (int)threadIdx.x;
  const int w = tid >> 6, l = tid & 63;
  const int quad = l >> 4, l16 = l & 15;
  const int wm = (w >> 1) * 64, wn = (w & 1) * 64;

  if (EPI == 0) {
#pragma unroll
    for (int ni = 0; ni < 4; ++ni) {
      const int col = n0 + wn + ni * 16 + l16;
      const float bv = bias[col];
#pragma unroll
      for (int mi = 0; mi < 4; ++mi) {
        const int row = m0 + wm + mi * 16 + quad * 4;
#pragma unroll
        for (int r = 0; r < 4; ++r)
          ((float*)C)[(size_t)(row + r) * N + col] = acc[mi][ni][r] + bv;
      }
    }
    return;
  }

  __syncthreads();
  unsigned short* sc = (w < 2) ? (As + w * 4608) : (Bs + (w - 2) * 4608);
  const int rr8 = l >> 3, c8 = (l & 7) * 8;
#pragma unroll
  for (int ni = 0; ni < 4; ++ni) {
    const int col = n0 + wn + ni * 16 + l16;
    const float bv = bias[col];
#pragma unroll
    for (int mi = 0; mi < 4; ++mi) {
#pragma unroll
      for (int r = 0; r < 4; ++r) {
        float v = acc[mi][ni][r] + bv;
        if (EPI == 2) v = v > 0.f ? v : 0.f;
        sc[(mi * 16 + quad * 4 + r) * 72 + ni * 16 + l16] = f2bf(v);
      }
    }
  }
  __syncthreads();
#pragma unroll
  for (int i = 0; i < 8; ++i) {
    bf16x8 vv = *(const bf16x8*)(sc + (i * 8 + rr8) * 72 + c8);
    const int row = m0 + wm + i * 8 + rr8;
    *(bf16x8*)((unsigned short*)C + (size_t)row * N + n0 + wn + c8) = vv;
  }
}

// --------------------------- fused QKV GEMM (128^2) ------------------------
// Grid 1536 = 64mt x 24nt. Chunked XCD map: 4x2 chunks of 16x12 tiles.
#define QSCALE 0.180336884f   // 0.125 * log2(e)

__global__ __launch_bounds__(256, 2) void gemm128_qkv(
    const unsigned short* __restrict__ A, const unsigned short* __restrict__ Bt,
    const float* __restrict__ qb, const float* __restrict__ kb,
    const float* __restrict__ vb, unsigned short* __restrict__ Qo,
    unsigned short* __restrict__ Ko, unsigned short* __restrict__ Vto, int K) {
  __shared__ unsigned short As[4 * 4096];
  __shared__ unsigned short Bs[4 * 4096];
  const int xcd = (int)blockIdx.x & 7, local = (int)blockIdx.x >> 3;  // 0..191
  const int mt = (xcd >> 1) * 16 + (local & 15);
  const int nt = (xcd & 1) * 12 + (local >> 4);
  const int m0 = mt * 128, n0 = nt * 128;

  f32x4 acc[4][4] = {};
  gemm128_core(A, Bt, As, Bs, m0, n0, K, acc);

  const int tid = (int)threadIdx.x;
  const int w = tid >> 6, l = tid & 63;
  const int quad = l >> 4, l16 = l & 15;
  const int wm = (w >> 1) * 64, wn = (w & 1) * 64;

  const int seg = n0 >> 10;                    // 0=Q, 1=K, 2=V (block-uniform)
  const float* bias = seg == 0 ? qb : (seg == 1 ? kb : vb);
  const int colb = (n0 + wn) & 1023;           // wave-uniform col base

  __syncthreads();   // close K-loop LDS use
  unsigned short* sc = (w < 2) ? (As + w * 4608) : (Bs + (w - 2) * 4608);
  const int rr8 = l >> 3, c8 = (l & 7) * 8;

  if (seg == 2) {
    // V: scratch transposed [dh][s]; readout runs along s (contiguous in Vto)
    const int b = m0 >> 11;                    // tile never crosses b (128|2048)
    const int hh = colb >> 6;
    const int s0 = (m0 & 2047) + wm;
#pragma unroll
    for (int ni = 0; ni < 4; ++ni) {
      const float bv = bias[colb + ni * 16 + l16];
#pragma unroll
      for (int mi = 0; mi < 4; ++mi) {
        union { ushort4 v; unsigned short u[4]; } pk;
#pragma unroll
        for (int r = 0; r < 4; ++r) pk.u[r] = f2bf(acc[mi][ni][r] + bv);
        *(ushort4*)(sc + (ni * 16 + l16) * 72 + mi * 16 + quad * 4) = pk.v;
      }
    }
    __syncthreads();
    unsigned short* vbase = Vto + ((size_t)(b * 16 + hh) * 64) * 2048;
#pragma unroll
    for (int i = 0; i < 8; ++i) {
      bf16x8 vv = *(const bf16x8*)(sc + (i * 8 + rr8) * 72 + c8);
      const int dh = i * 8 + rr8;
      *(bf16x8*)(vbase + (size_t)dh * 2048 + s0 + c8) = vv;
    }
  } else {
    // Q/K: row-major scratch, coalesced 128-B row stores
    unsigned short* Out = seg == 0 ? Qo : Ko;
#pragma unroll
    for (int ni = 0; ni < 4; ++ni) {
      const float bv = bias[colb + ni * 16 + l16];
#pragma unroll
      for (int mi = 0; mi < 4; ++mi) {
#pragma unroll
        for (int r = 0; r < 4; ++r) {
          float v = acc[mi][ni][r] + bv;
          if (seg == 0) v *= QSCALE;
          sc[(mi * 16 + quad * 4 + r) * 72 + ni * 16 + l16] = f2bf(v);
        }
      }
    }
    __syncthreads();
#pragma unroll
    for (int i = 0; i < 8; ++i) {
      bf16x8 vv = *(const bf16x8*)(sc + (i * 8 + rr8) * 72 + c8);
      const int row = m0 + wm + i * 8 + rr8;
      *(bf16x8*)(Out + (size_t)row * 1024 + colb + c8) = vv;
    }
  }
}

// --------------------------- flash attention (KVBLK=128) -------------------
__global__ __launch_bounds__(256, 2) void attn_fused(
    const unsigned short* __restrict__ Q, const unsigned short* __restrict__ K,
    const unsigned short* __restrict__ Vt, const int* __restrict__ lengths,
    unsigned short* __restrict__ ctx) {
  constexpr int S = 2048, D = 1024;
  __shared__ unsigned short Ks[128 * 72];       // [k=128][d=64 +pad]
  __shared__ unsigned short Vs[64 * 136];       // [dh=64][k=128 +pad]
  __shared__ unsigned short Ps[4 * 32 * 136];   // per-wave [q=32][k=128 +pad]

  const int tid = threadIdx.x;
  const int wave = tid >> 6, lane = tid & 63;
  const int quad = lane >> 4, l16 = lane & 15;
  const int bid = blockIdx.x;
  const int qt = bid & 15;
  const int h = (bid >> 4) & 15;
  const int b = bid >> 8;
  const int q0 = qt * 128;
  const int len = lengths[b];
  const int ktEnd = (len + 127) >> 7;
  const float NEGINF = -__builtin_inff();

  const size_t xbase = (size_t)b * S * D + (size_t)h * 64;
  const size_t vtb = (size_t)(b * 16 + h) * 64;

  bf16x8 qf0[2], qf1[2];
#pragma unroll
  for (int mb = 0; mb < 2; ++mb) {
    const unsigned short* qrow =
        Q + xbase + (size_t)(q0 + wave * 32 + mb * 16 + l16) * D;
    qf0[mb] = *(const bf16x8*)(qrow + quad * 8);
    qf1[mb] = *(const bf16x8*)(qrow + 32 + quad * 8);
  }

  // staging: K tile 128 rows(k) x 64 cols(d) = 4 int4/thread;
  //          V tile 64 rows(dh) x 128 cols(k) = 4 int4/thread.
  const int krw = tid >> 3, kcl = (tid & 7) * 8;
  const int vrw = tid >> 4, vcl = (tid & 15) * 8;
  const unsigned short* kg[4]; const unsigned short* vg[4];
  unsigned short* kd[4]; unsigned short* vd[4];
#pragma unroll
  for (int i = 0; i < 4; ++i) {
    kg[i] = K + xbase + (size_t)(i * 32 + krw) * D + kcl;
    kd[i] = Ks + (i * 32 + krw) * 72 + kcl;
    vg[i] = Vt + (vtb + i * 16 + vrw) * S + vcl;
    vd[i] = Vs + (i * 16 + vrw) * 136 + vcl;
  }

  f32x4 oacc[2][4] = {};
  float rs[2][4] = {};

  unsigned short* pw = Ps + wave * (32 * 136);

  int4 kr[4], vr[4];
#pragma unroll
  for (int i = 0; i < 4; ++i) {
    kr[i] = *(const int4*)(kg[i]);
    vr[i] = *(const int4*)(vg[i]);
  }

  for (int kt = 0; kt < ktEnd; ++kt) {
    const int k0 = kt * 128;
    __syncthreads();
#pragma unroll
    for (int i = 0; i < 4; ++i) {
      *(int4*)kd[i] = kr[i];
      *(int4*)vd[i] = vr[i];
    }
    __syncthreads();

    if (kt + 1 < ktEnd) {            // async prefetch of next tile
      const int kn = (kt + 1) * 128;
#pragma unroll
      for (int i = 0; i < 4; ++i) {
        kr[i] = *(const int4*)(kg[i] + (size_t)kn * D);
        vr[i] = *(const int4*)(vg[i] + kn);
      }
    }

    // QK^T + softmax in two 64-key register phases (no barriers between:
    // Ps is wave-private)
#pragma unroll
    for (int ph = 0; ph < 2; ++ph) {
      f32x4 sf[2][4];
      __builtin_amdgcn_s_setprio(1);
#pragma unroll
      for (int cb = 0; cb < 4; ++cb) {
        const int krow = ph * 64 + cb * 16 + l16;
        const bf16x8 kf0 = *(const bf16x8*)(Ks + krow * 72 + quad * 8);
        const bf16x8 kf1 = *(const bf16x8*)(Ks + krow * 72 + 32 + quad * 8);
#pragma unroll
        for (int mb = 0; mb < 2; ++mb) {
          f32x4 c = {0.f, 0.f, 0.f, 0.f};
          c = __builtin_amdgcn_mfma_f32_16x16x32_bf16(qf0[mb], kf0, c, 0, 0, 0);
          c = __builtin_amdgcn_mfma_f32_16x16x32_bf16(qf1[mb], kf1, c, 0, 0, 0);
          sf[mb][cb] = c;
        }
      }
      __builtin_amdgcn_s_setprio(0);

      if (k0 + ph * 64 + 64 > len) {
#pragma unroll
        for (int cb = 0; cb < 4; ++cb) {
          const bool msk = (k0 + ph * 64 + cb * 16 + l16) >= len;
#pragma unroll
          for (int mb = 0; mb < 2; ++mb)
#pragma unroll
            for (int r = 0; r < 4; ++r) sf[mb][cb][r] = msk ? NEGINF : sf[mb][cb][r];
        }
      }

#pragma unroll
      for (int mb = 0; mb < 2; ++mb)
#pragma unroll
        for (int cb = 0; cb < 4; ++cb)
#pragma unroll
          for (int r = 0; r < 4; ++r) {
            const float p = __builtin_amdgcn_exp2f(sf[mb][cb][r]);
            sf[mb][cb][r] = p;
            rs[mb][r] += p;
          }

#pragma unroll
      for (int mb = 0; mb < 2; ++mb)
#pragma unroll
        for (int cb = 0; cb < 4; ++cb)
#pragma unroll
          for (int r = 0; r < 4; ++r)
            pw[(mb * 16 + quad * 4 + r) * 136 + ph * 64 + cb * 16 + l16] =
                f2bf(sf[mb][cb][r]);
    }

    // PV over all 128 keys
    bf16x8 pa[2][4];
#pragma unroll
    for (int mb = 0; mb < 2; ++mb)
#pragma unroll
      for (int ks = 0; ks < 4; ++ks)
        pa[mb][ks] = *(const bf16x8*)(pw + (mb * 16 + l16) * 136 + ks * 32 + quad * 8);

    __builtin_amdgcn_s_setprio(1);
#pragma unroll
    for (int cb = 0; cb < 4; ++cb) {
#pragma unroll
      for (int ks = 0; ks < 4; ++ks) {
        const bf16x8 vbb =
            *(const bf16x8*)(Vs + (cb * 16 + l16) * 136 + ks * 32 + quad * 8);
#pragma unroll
        for (int mb = 0; mb < 2; ++mb)
          oacc[mb][cb] = __builtin_amdgcn_mfma_f32_16x16x32_bf16(
              pa[mb][ks], vbb, oacc[mb][cb], 0, 0, 0);
      }
    }
    __builtin_amdgcn_s_setprio(0);
  }

#pragma unroll
  for (int off = 8; off > 0; off >>= 1)
#pragma unroll
    for (int mb = 0; mb < 2; ++mb)
#pragma unroll
      for (int r = 0; r < 4; ++r) rs[mb][r] += __shfl_xor(rs[mb][r], off, 16);

#pragma unroll
  for (int mb = 0; mb < 2; ++mb) {
    float inv[4];
#pragma unroll
    for (int r = 0; r < 4; ++r) inv[r] = 1.0f / rs[mb][r];
#pragma unroll
    for (int cb = 0; cb < 4; ++cb)
#pragma unroll
      for (int r = 0; r < 4; ++r) {
        const int row = q0 + wave * 32 + mb * 16 + quad * 4 + r;
        ctx[xbase + (size_t)row * D + cb * 16 + l16] = f2bf(oacc[mb][cb][r] * inv[r]);
      }
  }
}

// ------------------------------ launcher -----------------------------------
extern "C" void kernel_launch(void* const* d_in, const int* in_sizes, int n_in,
                              void* d_out, int out_size, void* d_ws,
                              size_t ws_size, hipStream_t stream) {
  const float* x  = (const float*)d_in[0];
  const int* lengths = (const int*)d_in[1];
  const float* qW = (const float*)d_in[2];
  const float* qb = (const float*)d_in[3];
  const float* kW = (const float*)d_in[4];
  const float* kb = (const float*)d_in[5];
  const float* vW = (const float*)d_in[6];
  const float* vb = (const float*)d_in[7];
  const float* oW = (const float*)d_in[8];
  const float* ob = (const float*)d_in[9];
  const float* w1 = (const float*)d_in[10];
  const float* b1 = (const float*)d_in[11];
  const float* w2 = (const float*)d_in[12];
  const float* b2 = (const float*)d_in[13];
  float* out = (float*)d_out;

  const int Bx = 4, S = 2048, D = 1024, FF = 4096;
  const int M = Bx * S;  // 8192

  unsigned short* p = (unsigned short*)d_ws;
  unsigned short* xb  = p; p += (size_t)M * D;
  unsigned short* qWt = p; p += (size_t)D * D;   // contiguous [3072,1024]
  unsigned short* kWt = p; p += (size_t)D * D;
  unsigned short* vWt = p; p += (size_t)D * D;
  unsigned short* oWt = p; p += (size_t)D * D;
  unsigned short* w1t = p; p += (size_t)D * FF;   // [FF, D]
  unsigned short* w2t = p; p += (size_t)FF * D;   // [D, FF]
  unsigned short* Qb  = p; p += (size_t)M * D;
  unsigned short* Kb  = p; p += (size_t)M * D;
  unsigned short* Vtb = p; p += (size_t)M * D;    // [B,H,64,S]
  unsigned short* Cb  = p; p += (size_t)M * D;
  unsigned short* Ab  = p; p += (size_t)M * D;
  unsigned short* Hb  = p; p += (size_t)M * FF;

  {
    int n4 = (int)((size_t)M * D / 4);
    cast_f32_bf16<<<dim3((n4 + 255) / 256), dim3(256), 0, stream>>>(x, xb, n4);
  }
  prep_weights<<<dim3(6144), dim3(256), 0, stream>>>(
      qW, kW, vW, oW, w1, w2, qWt, kWt, vWt, oWt, w1t, w2t);

  // qkv: 128^2 reg-dbuf core, 24 x 64 = 1536 blocks
  gemm128_qkv<<<dim3(1536), dim3(256), 0, stream>>>(
      xb, qWt, qb, kb, vb, Qb, Kb, Vtb, D);

  attn_fused<<<dim3(Bx * 16 * (S / 128)), dim3(256), 0, stream>>>(
      Qb, Kb, Vtb, lengths, Cb);

  // proj: 128^2 reg-dbuf core, 8 x 64 = 512 blocks
  gemm128_bt<1><<<dim3(512), dim3(256), 0, stream>>>(Cb, oWt, ob, Ab, D, D);
  // ffn1: 256^2 8-phase core, 32 x 16 = 512 blocks
  gemm256_bt<2><<<dim3(512), dim3(512), 0, stream>>>(Ab, w1t, b1, Hb, FF, D);
  // ffn2: 128^2 reg-dbuf core, 8 x 64 = 512 blocks (K=4096: 128 K-steps)
  gemm128_bt<0><<<dim3(512), dim3(256), 0, stream>>>(Hb, w2t, b2, out, D, FF);
}

// Round 11
// 429.134 us; speedup vs baseline: 1.1160x; 1.1160x over previous
//
#include <hip/hip_runtime.h>

// ---------------------------------------------------------------------------
// TransformerEncoder: B=4, S=2048, D=1024, H=16, HD=64, FF=4096
// Round 16: attn reverted to R14 (KVBLK=128 spilled: WRITE_SIZE 239MB =
// scratch traffic, MfmaUtil 12%). 128^2 core: 4-buf -> 3-buf reg-dbuf
// (combining R10's measured 3-blocks/CU occupancy with R11's measured
// reg-dbuf). Ledger: step t = {vmcnt(4|0); barrier; DSR((t+1)%3 -> NXT
// bank); STAGE(t+3 -> buf t%3); MM(CUR bank)}. WAR: buf t%3's last read is
// DSR(t) issued at step t-1, closed at this step's barrier. vmcnt: at entry
// outstanding = {t+1,t+2} = 8 loads, vmcnt(4) => t+1 landed (tail: vmcnt(0)).
// LDS 48KB -> 3 blocks/CU; VGPR 88 (measured) < 168 cap @ 3 waves/SIMD.
// ffn1 (8-phase 256^2), chunked XCD maps, coalesced epilogues, cast, prep
// all unchanged from R14.
// ---------------------------------------------------------------------------

typedef short bf16x8 __attribute__((ext_vector_type(8)));
typedef float f32x4 __attribute__((ext_vector_type(4)));

__device__ __forceinline__ unsigned short f2bf(float f) {
  unsigned int u = __builtin_bit_cast(unsigned int, f);
  u += 0x7fffu + ((u >> 16) & 1u);   // round-to-nearest-even
  return (unsigned short)(u >> 16);
}

__device__ __forceinline__ void gload16(const unsigned short* g, unsigned short* l) {
  __builtin_amdgcn_global_load_lds(
      (const __attribute__((address_space(1))) unsigned int*)(g),
      (__attribute__((address_space(3))) unsigned int*)(l),
      16, 0, 0);
}

// --------------------------- cast fp32 -> bf16 -----------------------------
__global__ __launch_bounds__(256) void cast_f32_bf16(
    const float* __restrict__ src, unsigned short* __restrict__ dst, int n4) {
  int i = blockIdx.x * 256 + threadIdx.x;
  if (i < n4) {
    float4 f = ((const float4*)src)[i];
    ushort4 o;
    o.x = f2bf(f.x); o.y = f2bf(f.y); o.z = f2bf(f.z); o.w = f2bf(f.w);
    ((ushort4*)dst)[i] = o;
  }
}

// ---------------- merged weight prep: 6 transposes in one kernel -----------
__global__ __launch_bounds__(256) void prep_weights(
    const float* __restrict__ qW, const float* __restrict__ kW,
    const float* __restrict__ vW, const float* __restrict__ oW,
    const float* __restrict__ w1, const float* __restrict__ w2,
    unsigned short* __restrict__ qWt, unsigned short* __restrict__ kWt,
    unsigned short* __restrict__ vWt, unsigned short* __restrict__ oWt,
    unsigned short* __restrict__ w1t, unsigned short* __restrict__ w2t) {
  const int t = blockIdx.x;
  const float* W; unsigned short* Wt; int N, K, nt, kt;
  if (t < 2048) {
    const int w = t >> 9, r = t & 511;
    nt = r & 15; kt = r >> 4; N = 1024; K = 1024;
    W  = w == 0 ? qW : w == 1 ? kW : w == 2 ? vW : oW;
    Wt = w == 0 ? qWt : w == 1 ? kWt : w == 2 ? vWt : oWt;
  } else if (t < 4096) {
    const int r = t - 2048;
    nt = r & 63; kt = r >> 6; N = 4096; K = 1024; W = w1; Wt = w1t;
  } else {
    const int r = t - 4096;
    nt = r & 15; kt = r >> 4; N = 1024; K = 4096; W = w2; Wt = w2t;
  }
  const int wave = threadIdx.x >> 6, lane = threadIdx.x & 63;
  const int n = nt * 64 + lane;
  const int k0 = kt * 32 + wave * 8;
  union { int4 v; unsigned short u[8]; } s;
#pragma unroll
  for (int j = 0; j < 8; ++j) s.u[j] = f2bf(W[(size_t)(k0 + j) * N + n]);
  *(int4*)(Wt + (size_t)n * K + k0) = s.v;
}

// ---------------- 256x256 8-phase counted-vmcnt core (B^T) -----------------
// 8 waves 2Mx4N, wave tile 128x64 (8x4 frags), BK=64 (2 kk). R9-verified.
__device__ __forceinline__ void gemm256_8ph(
    const unsigned short* __restrict__ A, const unsigned short* __restrict__ Bt,
    unsigned short* __restrict__ As, unsigned short* __restrict__ Bs,
    const int m0, const int n0, const int K, f32x4 (&acc)[8][4]) {
  const int tid = (int)threadIdx.x;
  const int w = tid >> 6, l = tid & 63;
  const int quad = l >> 4, l16 = l & 15;
  const int wm = (w >> 2) * 128, wn = (w & 3) * 64;

  const int srow = w * 8 + (l >> 3);
  const int schunk = ((l & 7) ^ (l >> 3)) * 8;
  const unsigned short* gA = A + (size_t)(m0 + srow) * K + schunk;
  const unsigned short* gB = Bt + (size_t)(n0 + srow) * K + schunk;
  const int ldsW = w * 512;

  const int xr = l16 & 7;
  const int c0 = ((0 + quad) ^ xr) * 8;
  const int c1 = ((4 + quad) ^ xr) * 8;

  bf16x8 af[4][2], bf0[2][2], bf1[2][2];

  auto STA = [&](int buf, int a, int t) {
    gload16(gA + (size_t)(a * 64) * K + t * 64,
            As + buf * 16384 + a * 4096 + ldsW);
  };
  auto STB = [&](int buf, int a, int t) {
    gload16(gB + (size_t)(a * 64) * K + t * 64,
            Bs + buf * 16384 + a * 4096 + ldsW);
  };
  auto LDA = [&](int buf, int mh) {
    const unsigned short* p = As + buf * 16384 + (wm + mh * 64 + l16) * 64;
#pragma unroll
    for (int mi = 0; mi < 4; ++mi) {
      af[mi][0] = *(const bf16x8*)(p + mi * 16 * 64 + c0);
      af[mi][1] = *(const bf16x8*)(p + mi * 16 * 64 + c1);
    }
  };
  auto LDB = [&](int buf, int nh, bf16x8 (&bf)[2][2]) {
    const unsigned short* p = Bs + buf * 16384 + (wn + nh * 32 + l16) * 64;
#pragma unroll
    for (int ni = 0; ni < 2; ++ni) {
      bf[ni][0] = *(const bf16x8*)(p + ni * 16 * 64 + c0);
      bf[ni][1] = *(const bf16x8*)(p + ni * 16 * 64 + c1);
    }
  };
  auto MM = [&](int mh, int nh, bf16x8 (&bf)[2][2]) {
    __builtin_amdgcn_s_setprio(1);
#pragma unroll
    for (int mi = 0; mi < 4; ++mi)
#pragma unroll
      for (int ni = 0; ni < 2; ++ni) {
        f32x4& a = acc[mh * 4 + mi][nh * 2 + ni];
        a = __builtin_amdgcn_mfma_f32_16x16x32_bf16(af[mi][0], bf[ni][0], a, 0, 0, 0);
        a = __builtin_amdgcn_mfma_f32_16x16x32_bf16(af[mi][1], bf[ni][1], a, 0, 0, 0);
      }
    __builtin_amdgcn_s_setprio(0);
  };

  const int NK = K >> 6;   // >= 2
  STB(0, 0, 0); STB(0, 1, 0); STB(0, 2, 0); STB(0, 3, 0);
  STA(0, 0, 0); STA(0, 2, 0); STA(0, 1, 0); STA(0, 3, 0);
  asm volatile("s_waitcnt vmcnt(2)" ::: "memory");
  __builtin_amdgcn_s_barrier();

#pragma unroll 1
  for (int t = 0; t < NK; ++t) {
    const int c = t & 1, nb = c ^ 1;
    const bool st = (t + 1 < NK);
    // ---- P1 (mh0, nh0)
    LDA(c, 0); LDB(c, 0, bf0);
    if (st) { STB(nb, 0, t + 1); STB(nb, 1, t + 1); }
    __builtin_amdgcn_s_barrier();
    asm volatile("s_waitcnt lgkmcnt(0)" ::: "memory");
    __builtin_amdgcn_sched_barrier(0);
    MM(0, 0, bf0);
    __builtin_amdgcn_s_barrier();
    // ---- P2 (mh0, nh1)
    LDB(c, 1, bf1);
    if (st) { STB(nb, 2, t + 1); STB(nb, 3, t + 1); }
    __builtin_amdgcn_s_barrier();
    asm volatile("s_waitcnt lgkmcnt(0)" ::: "memory");
    __builtin_amdgcn_sched_barrier(0);
    MM(0, 1, bf1);
    if (st) asm volatile("s_waitcnt vmcnt(4)" ::: "memory");
    else    asm volatile("s_waitcnt vmcnt(0)" ::: "memory");
    __builtin_amdgcn_s_barrier();
    // ---- P3 (mh1, nh1)
    LDA(c, 1);
    if (st) { STA(nb, 0, t + 1); STA(nb, 2, t + 1); }
    __builtin_amdgcn_s_barrier();
    asm volatile("s_waitcnt lgkmcnt(0)" ::: "memory");
    __builtin_amdgcn_sched_barrier(0);
    MM(1, 1, bf1);
    __builtin_amdgcn_s_barrier();
    // ---- P4 (mh1, nh0)
    if (st) { STA(nb, 1, t + 1); STA(nb, 3, t + 1); }
    __builtin_amdgcn_s_barrier();
    MM(1, 0, bf0);
    if (st) asm volatile("s_waitcnt vmcnt(2)" ::: "memory");
    __builtin_amdgcn_s_barrier();
  }
}

// --------------------- 256^2 GEMM (B^T) — ffn1 only ------------------------
// Grid 512 = 32mt x 16nt. Chunked XCD map (R13): 4x2 chunks of 8x8 tiles.
template <int EPI>
__global__ __launch_bounds__(512, 1) void gemm256_bt(
    const unsigned short* __restrict__ A, const unsigned short* __restrict__ Bt,
    const float* __restrict__ bias, void* __restrict__ C, int N, int K) {
  __shared__ unsigned short As[2 * 16384];
  __shared__ unsigned short Bs[2 * 16384];
  const int xcd = (int)blockIdx.x & 7, local = (int)blockIdx.x >> 3;  // 0..63
  const int mt = (xcd >> 1) * 8 + (local >> 3);
  const int nt = (xcd & 1) * 8 + (local & 7);
  const int m0 = mt * 256, n0 = nt * 256;

  f32x4 acc[8][4] = {};
  gemm256_8ph(A, Bt, As, Bs, m0, n0, K, acc);

  const int tid = (int)threadIdx.x;
  const int w = tid >> 6, l = tid & 63;
  const int quad = l >> 4, l16 = l & 15;
  const int wm = (w >> 2) * 128, wn = (w & 3) * 64;

  if (EPI == 0) {
#pragma unroll
    for (int ni = 0; ni < 4; ++ni) {
      const int col = n0 + wn + ni * 16 + l16;
      const float bv = bias[col];
#pragma unroll
      for (int mi = 0; mi < 8; ++mi) {
        const int row = m0 + wm + mi * 16 + quad * 4;
#pragma unroll
        for (int r = 0; r < 4; ++r)
          ((float*)C)[(size_t)(row + r) * N + col] = acc[mi][ni][r] + bv;
      }
    }
    return;
  }

  // coalesced bf16 path (R12-verified)
  __syncthreads();
  unsigned short* sc = (w < 4) ? (As + w * 4608) : (Bs + (w - 4) * 4608);
  const int rr8 = l >> 3, c8 = (l & 7) * 8;
#pragma unroll
  for (int half = 0; half < 2; ++half) {
#pragma unroll
    for (int ni = 0; ni < 4; ++ni) {
      const int col = n0 + wn + ni * 16 + l16;
      const float bv = bias[col];
#pragma unroll
      for (int mi2 = 0; mi2 < 4; ++mi2) {
#pragma unroll
        for (int r = 0; r < 4; ++r) {
          float v = acc[half * 4 + mi2][ni][r] + bv;
          if (EPI == 2) v = v > 0.f ? v : 0.f;
          sc[(mi2 * 16 + quad * 4 + r) * 72 + ni * 16 + l16] = f2bf(v);
        }
      }
    }
    __syncthreads();
#pragma unroll
    for (int i = 0; i < 8; ++i) {
      bf16x8 vv = *(const bf16x8*)(sc + (i * 8 + rr8) * 72 + c8);
      const int row = m0 + wm + half * 64 + i * 8 + rr8;
      *(bf16x8*)((unsigned short*)C + (size_t)row * N + n0 + wn + c8) = vv;
    }
    __syncthreads();
  }
}

// ------ 128x128 3-buf reg-double-buffered GEMM core (48 KB, 3 blk/CU) ------
__device__ __forceinline__ void gemm128_core(
    const unsigned short* __restrict__ A, const unsigned short* __restrict__ Bt,
    unsigned short* __restrict__ As, unsigned short* __restrict__ Bs,
    const int m0, const int n0, const int K, f32x4 (&acc)[4][4]) {
  const int tid = (int)threadIdx.x;
  const int w = tid >> 6, l = tid & 63;
  const int quad = l >> 4, l16 = l & 15;
  const int wm = (w >> 1) * 64, wn = (w & 1) * 64;

  const int lr = l >> 2, lc = l & 3;
  const int swz = (lc ^ ((l >> 3) & 3)) * 8;
  const unsigned short* gA[2]; const unsigned short* gB[2];
  unsigned short* dA[2]; unsigned short* dB[2];
#pragma unroll
  for (int j = 0; j < 2; ++j) {
    const int rr = (w * 2 + j) * 16 + lr;
    gA[j] = A + (size_t)(m0 + rr) * K + swz;
    gB[j] = Bt + (size_t)(n0 + rr) * K + swz;
    dA[j] = As + (w * 2 + j) * 512;
    dB[j] = Bs + (w * 2 + j) * 512;
  }

  const int cread = (quad ^ ((l16 >> 1) & 3)) * 8;
  const int rA = (wm + l16) * 32;
  const int rB = (wn + l16) * 32;

  auto STAGE = [&](int db, int t) {
#pragma unroll
    for (int j = 0; j < 2; ++j) {
      gload16(gA[j] + t * 32, dA[j] + db * 4096);
      gload16(gB[j] + t * 32, dB[j] + db * 4096);
    }
  };
  auto DSR = [&](int db, bf16x8 (&af)[4], bf16x8 (&bf)[4]) {
    const unsigned short* pa = As + db * 4096 + rA + cread;
    const unsigned short* pb = Bs + db * 4096 + rB + cread;
#pragma unroll
    for (int ni = 0; ni < 4; ++ni) bf[ni] = *(const bf16x8*)(pb + ni * 16 * 32);
#pragma unroll
    for (int mi = 0; mi < 4; ++mi) af[mi] = *(const bf16x8*)(pa + mi * 16 * 32);
  };
  auto MM = [&](bf16x8 (&af)[4], bf16x8 (&bf)[4]) {
    __builtin_amdgcn_s_setprio(1);
#pragma unroll
    for (int mi = 0; mi < 4; ++mi)
#pragma unroll
      for (int ni = 0; ni < 4; ++ni)
        acc[mi][ni] = __builtin_amdgcn_mfma_f32_16x16x32_bf16(
            af[mi], bf[ni], acc[mi][ni], 0, 0, 0);
    __builtin_amdgcn_s_setprio(0);
  };

  bf16x8 afA[4], bfA[4], afB[4], bfB[4];

  const int NK = K >> 5;   // even, >= 4
  STAGE(0, 0); STAGE(1, 1); STAGE(2, 2);
  asm volatile("s_waitcnt vmcnt(8)" ::: "memory");
  __builtin_amdgcn_s_barrier();
  DSR(0, afA, bfA);

  // cdr = (t+1)%3 (DSR buf), cst = t%3 (STAGE target for tile t+3)
  int cdr = 1, cst = 0;
#define STEP128(T, afC, bfC, afN, bfN)                                \
  {                                                                   \
    const int t_ = (T);                                               \
    if (t_ + 2 < NK) asm volatile("s_waitcnt vmcnt(4)" ::: "memory"); \
    else             asm volatile("s_waitcnt vmcnt(0)" ::: "memory"); \
    __builtin_amdgcn_s_barrier();                                     \
    DSR(cdr, afN, bfN);                                               \
    if (t_ + 3 < NK) STAGE(cst, t_ + 3);                              \
    MM(afC, bfC);                                                     \
    cdr = cdr == 2 ? 0 : cdr + 1;                                     \
    cst = cst == 2 ? 0 : cst + 1;                                     \
  }

#pragma unroll 1
  for (int t = 0; t < NK - 2; t += 2) {
    STEP128(t, afA, bfA, afB, bfB);
    STEP128(t + 1, afB, bfB, afA, bfA);
  }
  STEP128(NK - 2, afA, bfA, afB, bfB);
  MM(afB, bfB);
#undef STEP128
}

// --------------------- 128^2 GEMM (B^T) — proj, ffn2 -----------------------
// Grid 512 = 64mt x 8nt. Chunked XCD map: 8x1 chunks of 8x8 tiles.
template <int EPI>
__global__ __launch_bounds__(256, 3) void gemm128_bt(
    const unsigned short* __restrict__ A, const unsigned short* __restrict__ Bt,
    const float* __restrict__ bias, void* __restrict__ C, int N, int K) {
  __shared__ unsigned short As[3 * 4096];
  __shared__ unsigned short Bs[3 * 4096];
  const int xcd = (int)blockIdx.x & 7, local = (int)blockIdx.x >> 3;  // 0..63
  const int mt = xcd * 8 + (local >> 3);
  const int nt = local & 7;
  const int m0 = mt * 128, n0 = nt * 128;

  f32x4 acc[4][4] = {};
  gemm128_core(A, Bt, As, Bs, m0, n0, K, acc);

  const int tid = (int)threadIdx.x;
  const int w = tid >> 6, l = tid & 63;
  const int quad = l >> 4, l16 = l & 15;
  const int wm = (w >> 1) * 64, wn = (w & 1) * 64;

  if (EPI == 0) {
#pragma unroll
    for (int ni = 0; ni < 4; ++ni) {
      const int col = n0 + wn + ni * 16 + l16;
      const float bv = bias[col];
#pragma unroll
      for (int mi = 0; mi < 4; ++mi) {
        const int row = m0 + wm + mi * 16 + quad * 4;
#pragma unroll
        for (int r = 0; r < 4; ++r)
          ((float*)C)[(size_t)(row + r) * N + col] = acc[mi][ni][r] + bv;
      }
    }
    return;
  }

  __syncthreads();
  unsigned short* sc = (w < 2) ? (As + w * 4608) : (Bs + (w - 2) * 4608);
  const int rr8 = l >> 3, c8 = (l & 7) * 8;
#pragma unroll
  for (int ni = 0; ni < 4; ++ni) {
    const int col = n0 + wn + ni * 16 + l16;
    const float bv = bias[col];
#pragma unroll
    for (int mi = 0; mi < 4; ++mi) {
#pragma unroll
      for (int r = 0; r < 4; ++r) {
        float v = acc[mi][ni][r] + bv;
        if (EPI == 2) v = v > 0.f ? v : 0.f;
        sc[(mi * 16 + quad * 4 + r) * 72 + ni * 16 + l16] = f2bf(v);
      }
    }
  }
  __syncthreads();
#pragma unroll
  for (int i = 0; i < 8; ++i) {
    bf16x8 vv = *(const bf16x8*)(sc + (i * 8 + rr8) * 72 + c8);
    const int row = m0 + wm + i * 8 + rr8;
    *(bf16x8*)((unsigned short*)C + (size_t)row * N + n0 + wn + c8) = vv;
  }
}

// --------------------------- fused QKV GEMM (128^2) ------------------------
// Grid 1536 = 64mt x 24nt. Chunked XCD map: 4x2 chunks of 16x12 tiles.
#define QSCALE 0.180336884f   // 0.125 * log2(e)

__global__ __launch_bounds__(256, 3) void gemm128_qkv(
    const unsigned short* __restrict__ A, const unsigned short* __restrict__ Bt,
    const float* __restrict__ qb, const float* __restrict__ kb,
    const float* __restrict__ vb, unsigned short* __restrict__ Qo,
    unsigned short* __restrict__ Ko, unsigned short* __restrict__ Vto, int K) {
  __shared__ unsigned short As[3 * 4096];
  __shared__ unsigned short Bs[3 * 4096];
  const int xcd = (int)blockIdx.x & 7, local = (int)blockIdx.x >> 3;  // 0..191
  const int mt = (xcd >> 1) * 16 + (local & 15);
  const int nt = (xcd & 1) * 12 + (local >> 4);
  const int m0 = mt * 128, n0 = nt * 128;

  f32x4 acc[4][4] = {};
  gemm128_core(A, Bt, As, Bs, m0, n0, K, acc);

  const int tid = (int)threadIdx.x;
  const int w = tid >> 6, l = tid & 63;
  const int quad = l >> 4, l16 = l & 15;
  const int wm = (w >> 1) * 64, wn = (w & 1) * 64;

  const int seg = n0 >> 10;                    // 0=Q, 1=K, 2=V (block-uniform)
  const float* bias = seg == 0 ? qb : (seg == 1 ? kb : vb);
  const int colb = (n0 + wn) & 1023;           // wave-uniform col base

  __syncthreads();   // close K-loop LDS use
  unsigned short* sc = (w < 2) ? (As + w * 4608) : (Bs + (w - 2) * 4608);
  const int rr8 = l >> 3, c8 = (l & 7) * 8;

  if (seg == 2) {
    // V: scratch transposed [dh][s]; readout runs along s (contiguous in Vto)
    const int b = m0 >> 11;                    // tile never crosses b (128|2048)
    const int hh = colb >> 6;
    const int s0 = (m0 & 2047) + wm;
#pragma unroll
    for (int ni = 0; ni < 4; ++ni) {
      const float bv = bias[colb + ni * 16 + l16];
#pragma unroll
      for (int mi = 0; mi < 4; ++mi) {
        union { ushort4 v; unsigned short u[4]; } pk;
#pragma unroll
        for (int r = 0; r < 4; ++r) pk.u[r] = f2bf(acc[mi][ni][r] + bv);
        *(ushort4*)(sc + (ni * 16 + l16) * 72 + mi * 16 + quad * 4) = pk.v;
      }
    }
    __syncthreads();
    unsigned short* vbase = Vto + ((size_t)(b * 16 + hh) * 64) * 2048;
#pragma unroll
    for (int i = 0; i < 8; ++i) {
      bf16x8 vv = *(const bf16x8*)(sc + (i * 8 + rr8) * 72 + c8);
      const int dh = i * 8 + rr8;
      *(bf16x8*)(vbase + (size_t)dh * 2048 + s0 + c8) = vv;
    }
  } else {
    // Q/K: row-major scratch, coalesced 128-B row stores
    unsigned short* Out = seg == 0 ? Qo : Ko;
#pragma unroll
    for (int ni = 0; ni < 4; ++ni) {
      const float bv = bias[colb + ni * 16 + l16];
#pragma unroll
      for (int mi = 0; mi < 4; ++mi) {
#pragma unroll
        for (int r = 0; r < 4; ++r) {
          float v = acc[mi][ni][r] + bv;
          if (seg == 0) v *= QSCALE;
          sc[(mi * 16 + quad * 4 + r) * 72 + ni * 16 + l16] = f2bf(v);
        }
      }
    }
    __syncthreads();
#pragma unroll
    for (int i = 0; i < 8; ++i) {
      bf16x8 vv = *(const bf16x8*)(sc + (i * 8 + rr8) * 72 + c8);
      const int row = m0 + wm + i * 8 + rr8;
      *(bf16x8*)(Out + (size_t)row * 1024 + colb + c8) = vv;
    }
  }
}

// --------------------------- flash attention (R14) -------------------------
__global__ __launch_bounds__(256, 4) void attn_fused(
    const unsigned short* __restrict__ Q, const unsigned short* __restrict__ K,
    const unsigned short* __restrict__ Vt, const int* __restrict__ lengths,
    unsigned short* __restrict__ ctx) {
  constexpr int S = 2048, D = 1024;
  __shared__ unsigned short Ks[64 * 72];
  __shared__ unsigned short Vs[64 * 72];
  __shared__ unsigned short Ps[4 * 32 * 72];

  const int tid = threadIdx.x;
  const int wave = tid >> 6, lane = tid & 63;
  const int quad = lane >> 4, l16 = lane & 15;
  const int bid = blockIdx.x;
  const int qt = bid & 15;
  const int h = (bid >> 4) & 15;
  const int b = bid >> 8;
  const int q0 = qt * 128;
  const int len = lengths[b];
  const int ktEnd = (len + 63) >> 6;
  const float NEGINF = -__builtin_inff();

  const size_t xbase = (size_t)b * S * D + (size_t)h * 64;
  const size_t vtb = (size_t)(b * 16 + h) * 64;

  bf16x8 qf0[2], qf1[2];
#pragma unroll
  for (int mb = 0; mb < 2; ++mb) {
    const unsigned short* qrow =
        Q + xbase + (size_t)(q0 + wave * 32 + mb * 16 + l16) * D;
    qf0[mb] = *(const bf16x8*)(qrow + quad * 8);
    qf1[mb] = *(const bf16x8*)(qrow + 32 + quad * 8);
  }

  const int sr1 = tid >> 3, sc1 = (tid & 7) * 8;
  const int sr2 = (256 + tid) >> 3, sc2 = (tid & 7) * 8;
  const unsigned short* kg1 = K + xbase + (size_t)sr1 * D + sc1;
  const unsigned short* kg2 = K + xbase + (size_t)sr2 * D + sc2;
  const unsigned short* vg1 = Vt + (vtb + sr1) * S + sc1;
  const unsigned short* vg2 = Vt + (vtb + sr2) * S + sc2;

  f32x4 oacc[2][4] = {};
  float rs[2][4] = {};

  unsigned short* pw = Ps + wave * (32 * 72);

  int4 kr1, kr2, vr1, vr2;
  {
    kr1 = *(const int4*)(kg1);
    kr2 = *(const int4*)(kg2);
    vr1 = *(const int4*)(vg1);
    vr2 = *(const int4*)(vg2);
  }

  for (int kt = 0; kt < ktEnd; ++kt) {
    const int k0 = kt * 64;
    __syncthreads();
    *(int4*)(Ks + sr1 * 72 + sc1) = kr1;
    *(int4*)(Ks + sr2 * 72 + sc2) = kr2;
    *(int4*)(Vs + sr1 * 72 + sc1) = vr1;
    *(int4*)(Vs + sr2 * 72 + sc2) = vr2;
    __syncthreads();

    if (kt + 1 < ktEnd) {            // async prefetch of next tile
      const int kn = (kt + 1) * 64;
      kr1 = *(const int4*)(kg1 + (size_t)kn * D);
      kr2 = *(const int4*)(kg2 + (size_t)kn * D);
      vr1 = *(const int4*)(vg1 + kn);
      vr2 = *(const int4*)(vg2 + kn);
    }

    f32x4 sf[2][4];
    __builtin_amdgcn_s_setprio(1);
#pragma unroll
    for (int cb = 0; cb < 4; ++cb) {
      const bf16x8 kf0 = *(const bf16x8*)(Ks + (cb * 16 + l16) * 72 + quad * 8);
      const bf16x8 kf1 = *(const bf16x8*)(Ks + (cb * 16 + l16) * 72 + 32 + quad * 8);
#pragma unroll
      for (int mb = 0; mb < 2; ++mb) {
        f32x4 c = {0.f, 0.f, 0.f, 0.f};
        c = __builtin_amdgcn_mfma_f32_16x16x32_bf16(qf0[mb], kf0, c, 0, 0, 0);
        c = __builtin_amdgcn_mfma_f32_16x16x32_bf16(qf1[mb], kf1, c, 0, 0, 0);
        sf[mb][cb] = c;
      }
    }
    __builtin_amdgcn_s_setprio(0);

    if (k0 + 64 > len) {
#pragma unroll
      for (int cb = 0; cb < 4; ++cb) {
        const bool msk = (k0 + cb * 16 + l16) >= len;
#pragma unroll
        for (int mb = 0; mb < 2; ++mb)
#pragma unroll
          for (int r = 0; r < 4; ++r) sf[mb][cb][r] = msk ? NEGINF : sf[mb][cb][r];
      }
    }

#pragma unroll
    for (int mb = 0; mb < 2; ++mb)
#pragma unroll
      for (int cb = 0; cb < 4; ++cb)
#pragma unroll
        for (int r = 0; r < 4; ++r) {
          const float p = __builtin_amdgcn_exp2f(sf[mb][cb][r]);
          sf[mb][cb][r] = p;
          rs[mb][r] += p;
        }

#pragma unroll
    for (int mb = 0; mb < 2; ++mb)
#pragma unroll
      for (int cb = 0; cb < 4; ++cb)
#pragma unroll
        for (int r = 0; r < 4; ++r)
          pw[(mb * 16 + quad * 4 + r) * 72 + cb * 16 + l16] = f2bf(sf[mb][cb][r]);

    bf16x8 pa0[2], pa1[2];
#pragma unroll
    for (int mb = 0; mb < 2; ++mb) {
      pa0[mb] = *(const bf16x8*)(pw + (mb * 16 + l16) * 72 + quad * 8);
      pa1[mb] = *(const bf16x8*)(pw + (mb * 16 + l16) * 72 + 32 + quad * 8);
    }
    __builtin_amdgcn_s_setprio(1);
#pragma unroll
    for (int cb = 0; cb < 4; ++cb) {
      const bf16x8 vb0 = *(const bf16x8*)(Vs + (cb * 16 + l16) * 72 + quad * 8);
      const bf16x8 vb1 = *(const bf16x8*)(Vs + (cb * 16 + l16) * 72 + 32 + quad * 8);
#pragma unroll
      for (int mb = 0; mb < 2; ++mb) {
        oacc[mb][cb] = __builtin_amdgcn_mfma_f32_16x16x32_bf16(pa0[mb], vb0, oacc[mb][cb], 0, 0, 0);
        oacc[mb][cb] = __builtin_amdgcn_mfma_f32_16x16x32_bf16(pa1[mb], vb1, oacc[mb][cb], 0, 0, 0);
      }
    }
    __builtin_amdgcn_s_setprio(0);
  }

#pragma unroll
  for (int off = 8; off > 0; off >>= 1)
#pragma unroll
    for (int mb = 0; mb < 2; ++mb)
#pragma unroll
      for (int r = 0; r < 4; ++r) rs[mb][r] += __shfl_xor(rs[mb][r], off, 16);

#pragma unroll
  for (int mb = 0; mb < 2; ++mb) {
    float inv[4];
#pragma unroll
    for (int r = 0; r < 4; ++r) inv[r] = 1.0f / rs[mb][r];
#pragma unroll
    for (int cb = 0; cb < 4; ++cb)
#pragma unroll
      for (int r = 0; r < 4; ++r) {
        const int row = q0 + wave * 32 + mb * 16 + quad * 4 + r;
        ctx[xbase + (size_t)row * D + cb * 16 + l16] = f2bf(oacc[mb][cb][r] * inv[r]);
      }
  }
}

// ------------------------------ launcher -----------------------------------
extern "C" void kernel_launch(void* const* d_in, const int* in_sizes, int n_in,
                              void* d_out, int out_size, void* d_ws,
                              size_t ws_size, hipStream_t stream) {
  const float* x  = (const float*)d_in[0];
  const int* lengths = (const int*)d_in[1];
  const float* qW = (const float*)d_in[2];
  const float* qb = (const float*)d_in[3];
  const float* kW = (const float*)d_in[4];
  const float* kb = (const float*)d_in[5];
  const float* vW = (const float*)d_in[6];
  const float* vb = (const float*)d_in[7];
  const float* oW = (const float*)d_in[8];
  const float* ob = (const float*)d_in[9];
  const float* w1 = (const float*)d_in[10];
  const float* b1 = (const float*)d_in[11];
  const float* w2 = (const float*)d_in[12];
  const float* b2 = (const float*)d_in[13];
  float* out = (float*)d_out;

  const int Bx = 4, S = 2048, D = 1024, FF = 4096;
  const int M = Bx * S;  // 8192

  unsigned short* p = (unsigned short*)d_ws;
  unsigned short* xb  = p; p += (size_t)M * D;
  unsigned short* qWt = p; p += (size_t)D * D;   // contiguous [3072,1024]
  unsigned short* kWt = p; p += (size_t)D * D;
  unsigned short* vWt = p; p += (size_t)D * D;
  unsigned short* oWt = p; p += (size_t)D * D;
  unsigned short* w1t = p; p += (size_t)D * FF;   // [FF, D]
  unsigned short* w2t = p; p += (size_t)FF * D;   // [D, FF]
  unsigned short* Qb  = p; p += (size_t)M * D;
  unsigned short* Kb  = p; p += (size_t)M * D;
  unsigned short* Vtb = p; p += (size_t)M * D;    // [B,H,64,S]
  unsigned short* Cb  = p; p += (size_t)M * D;
  unsigned short* Ab  = p; p += (size_t)M * D;
  unsigned short* Hb  = p; p += (size_t)M * FF;

  {
    int n4 = (int)((size_t)M * D / 4);
    cast_f32_bf16<<<dim3((n4 + 255) / 256), dim3(256), 0, stream>>>(x, xb, n4);
  }
  prep_weights<<<dim3(6144), dim3(256), 0, stream>>>(
      qW, kW, vW, oW, w1, w2, qWt, kWt, vWt, oWt, w1t, w2t);

  // qkv: 128^2 3-buf reg-dbuf core, 24 x 64 = 1536 blocks (3 blk/CU)
  gemm128_qkv<<<dim3(1536), dim3(256), 0, stream>>>(
      xb, qWt, qb, kb, vb, Qb, Kb, Vtb, D);

  attn_fused<<<dim3(Bx * 16 * (S / 128)), dim3(256), 0, stream>>>(
      Qb, Kb, Vtb, lengths, Cb);

  // proj: 128^2 3-buf reg-dbuf core, 8 x 64 = 512 blocks
  gemm128_bt<1><<<dim3(512), dim3(256), 0, stream>>>(Cb, oWt, ob, Ab, D, D);
  // ffn1: 256^2 8-phase core, 32 x 16 = 512 blocks
  gemm256_bt<2><<<dim3(512), dim3(512), 0, stream>>>(Ab, w1t, b1, Hb, FF, D);
  // ffn2: 128^2 3-buf reg-dbuf core, 8 x 64 = 512 blocks (K=4096: 128 steps)
  gemm128_bt<0><<<dim3(512), dim3(256), 0, stream>>>(Hb, w2t, b2, out, D, FF);
}